// Round 1
// baseline (1747.595 us; speedup 1.0000x reference)
//
#include <hip/hip_runtime.h>

#define SEQ   2048
#define EMB   1024
#define NH    16
#define HD    64
#define BATCH 4

// ---------------------------------------------------------------------------
// Projection GEMM: Y = X @ W^T + bias.
// X: [M, EMB] row-major. W: [EMB, EMB] row-major (out_features, in_features).
// MODE 0: scatter Y into [b, h, s, d] layout (head split). MODE 1: plain [m, n].
// 128x128 tile, BK=16, 256 threads, 8x8 accum per thread. fp32 VALU.
// ---------------------------------------------------------------------------
template <int MODE>
__global__ __launch_bounds__(256) void mha_proj_kernel(
    const float* __restrict__ X, const float* __restrict__ W,
    const float* __restrict__ bias, float* __restrict__ Y) {
  const int BM = 128, BK = 16;
  __shared__ float As[BK][BM];  // As[k][m]  (transposed for vector compute reads)
  __shared__ float Bs[BK][BM];  // Bs[k][n]
  const int t = threadIdx.x;
  const int tx = t & 15, ty = t >> 4;
  const int m0 = blockIdx.y * BM, n0 = blockIdx.x * BM;

  float acc[8][8];
#pragma unroll
  for (int i = 0; i < 8; ++i)
#pragma unroll
    for (int j = 0; j < 8; ++j) acc[i][j] = 0.f;

  for (int k0 = 0; k0 < EMB; k0 += BK) {
#pragma unroll
    for (int it = 0; it < 2; ++it) {
      const int f = t + 256 * it;      // 0..511 : 128 rows x 4 float4-slots
      const int row = f >> 2, slot = f & 3;
      const float4 av =
          *(const float4*)(X + (size_t)(m0 + row) * EMB + k0 + slot * 4);
      As[slot * 4 + 0][row] = av.x;
      As[slot * 4 + 1][row] = av.y;
      As[slot * 4 + 2][row] = av.z;
      As[slot * 4 + 3][row] = av.w;
      const float4 bv =
          *(const float4*)(W + (size_t)(n0 + row) * EMB + k0 + slot * 4);
      Bs[slot * 4 + 0][row] = bv.x;
      Bs[slot * 4 + 1][row] = bv.y;
      Bs[slot * 4 + 2][row] = bv.z;
      Bs[slot * 4 + 3][row] = bv.w;
    }
    __syncthreads();
#pragma unroll
    for (int kk = 0; kk < BK; ++kk) {
      const float4 a0 = *(const float4*)&As[kk][ty * 8];
      const float4 a1 = *(const float4*)&As[kk][ty * 8 + 4];
      const float4 b0 = *(const float4*)&Bs[kk][tx * 8];
      const float4 b1 = *(const float4*)&Bs[kk][tx * 8 + 4];
      const float a[8] = {a0.x, a0.y, a0.z, a0.w, a1.x, a1.y, a1.z, a1.w};
      const float b[8] = {b0.x, b0.y, b0.z, b0.w, b1.x, b1.y, b1.z, b1.w};
#pragma unroll
      for (int i = 0; i < 8; ++i)
#pragma unroll
        for (int j = 0; j < 8; ++j) acc[i][j] += a[i] * b[j];
    }
    __syncthreads();
  }

  const int nbase = n0 + tx * 8;
  float bb[8];
#pragma unroll
  for (int j = 0; j < 8; ++j) bb[j] = bias[nbase + j];
#pragma unroll
  for (int i = 0; i < 8; ++i) {
    const int m = m0 + ty * 8 + i;
    const float4 v0 = make_float4(acc[i][0] + bb[0], acc[i][1] + bb[1],
                                  acc[i][2] + bb[2], acc[i][3] + bb[3]);
    const float4 v1 = make_float4(acc[i][4] + bb[4], acc[i][5] + bb[5],
                                  acc[i][6] + bb[6], acc[i][7] + bb[7]);
    if (MODE == 0) {
      // n = h*64 + d ; 8 cols never straddle a head (8 | 64).
      const int h = nbase >> 6, d = nbase & 63;
      const int b = m >> 11, s = m & (SEQ - 1);
      float* dst = Y + (((size_t)(b * NH + h) * SEQ + s) * HD + d);
      *(float4*)dst = v0;
      *(float4*)(dst + 4) = v1;
    } else {
      float* dst = Y + (size_t)m * EMB + nbase;
      *(float4*)dst = v0;
      *(float4*)(dst + 4) = v1;
    }
  }
}

// ---------------------------------------------------------------------------
// Causal flash attention, fp32. One block = one (bh, 64-row q-tile).
// Q/K/V in [b, h, s, d] layout. Output written merged: [b, s, h*64+d].
// 256 threads; thread (tx,ty) owns score/O rows ty*4..+3, cols tx*4..+3.
// P tile reuses the K LDS buffer (K is dead after the score phase).
// ---------------------------------------------------------------------------
__global__ __launch_bounds__(256) void mha_attn_kernel(
    const float* __restrict__ Q, const float* __restrict__ K,
    const float* __restrict__ V, float* __restrict__ O) {
  __shared__ float Qt[64 * 64];  // Qt[d*64 + r]       = Q[r][d]
  __shared__ float KP[64 * 68];  // Kt[d*68 + j] = K[j][d]; later Pt[c*68 + r]
  __shared__ float Vs[64 * 64];  // Vs[j*64 + d]

  const int qt = blockIdx.x, bh = blockIdx.y;
  const int t = threadIdx.x, tx = t & 15, ty = t >> 4;
  const size_t base = (size_t)bh * SEQ * HD;
  const float* Qb = Q + base + (size_t)qt * 64 * HD;
  const float* Kb = K + base;
  const float* Vb = V + base;

  {  // Q tile, transposed store (bank = j%32 -> 2-way, free)
    const int j = t & 63, dg = t >> 6;
#pragma unroll
    for (int dd = 0; dd < 4; ++dd) {
      const int d4 = dg + dd * 4;
      const float4 v = *(const float4*)(Qb + (size_t)j * HD + d4 * 4);
      Qt[(d4 * 4 + 0) * 64 + j] = v.x;
      Qt[(d4 * 4 + 1) * 64 + j] = v.y;
      Qt[(d4 * 4 + 2) * 64 + j] = v.z;
      Qt[(d4 * 4 + 3) * 64 + j] = v.w;
    }
  }

  float m_run[4], l_run[4], o_acc[4][4];
#pragma unroll
  for (int i = 0; i < 4; ++i) {
    m_run[i] = -INFINITY;
    l_run[i] = 0.f;
#pragma unroll
    for (int j = 0; j < 4; ++j) o_acc[i][j] = 0.f;
  }

  for (int kt = 0; kt <= qt; ++kt) {
    __syncthreads();  // previous tile's P/V reads done before overwrite
    {                 // K transposed, V natural
      const int j = t & 63, dg = t >> 6;
      const float* srcK = Kb + (size_t)(kt * 64 + j) * HD;
#pragma unroll
      for (int dd = 0; dd < 4; ++dd) {
        const int d4 = dg + dd * 4;
        const float4 v = *(const float4*)(srcK + d4 * 4);
        KP[(d4 * 4 + 0) * 68 + j] = v.x;
        KP[(d4 * 4 + 1) * 68 + j] = v.y;
        KP[(d4 * 4 + 2) * 68 + j] = v.z;
        KP[(d4 * 4 + 3) * 68 + j] = v.w;
      }
      const int jv = t >> 4, d4 = t & 15;
#pragma unroll
      for (int it = 0; it < 4; ++it) {
        const int jr = jv + 16 * it;
        const float4 v =
            *(const float4*)(Vb + (size_t)(kt * 64 + jr) * HD + d4 * 4);
        *(float4*)&Vs[jr * 64 + d4 * 4] = v;
      }
    }
    __syncthreads();

    // ---- scores: s[i][j] = Q[r0+i] . K[c0+j] ----
    float s[4][4] = {{0.f, 0.f, 0.f, 0.f},
                     {0.f, 0.f, 0.f, 0.f},
                     {0.f, 0.f, 0.f, 0.f},
                     {0.f, 0.f, 0.f, 0.f}};
#pragma unroll 8
    for (int d = 0; d < 64; ++d) {
      const float4 qv = *(const float4*)&Qt[d * 64 + ty * 4];
      const float4 kv = *(const float4*)&KP[d * 68 + tx * 4];
      const float qa[4] = {qv.x, qv.y, qv.z, qv.w};
      const float ka[4] = {kv.x, kv.y, kv.z, kv.w};
#pragma unroll
      for (int i = 0; i < 4; ++i)
#pragma unroll
        for (int j = 0; j < 4; ++j) s[i][j] += qa[i] * ka[j];
    }

    const float scale = 0.125f;  // 1/sqrt(64)
#pragma unroll
    for (int i = 0; i < 4; ++i)
#pragma unroll
      for (int j = 0; j < 4; ++j) {
        float x = s[i][j] * scale;
        if (kt == qt && (tx * 4 + j) > (ty * 4 + i)) x = -1e9f;  // causal
        s[i][j] = x;
      }

    // ---- online softmax (row reduce over the 16 tx-lanes) ----
#pragma unroll
    for (int i = 0; i < 4; ++i) {
      float tm = fmaxf(fmaxf(s[i][0], s[i][1]), fmaxf(s[i][2], s[i][3]));
      tm = fmaxf(tm, __shfl_xor(tm, 1));
      tm = fmaxf(tm, __shfl_xor(tm, 2));
      tm = fmaxf(tm, __shfl_xor(tm, 4));
      tm = fmaxf(tm, __shfl_xor(tm, 8));
      const float mnew = fmaxf(m_run[i], tm);
      const float alpha = __expf(m_run[i] - mnew);
      m_run[i] = mnew;
      float rs = 0.f;
#pragma unroll
      for (int j = 0; j < 4; ++j) {
        s[i][j] = __expf(s[i][j] - mnew);
        rs += s[i][j];
      }
      rs += __shfl_xor(rs, 1);
      rs += __shfl_xor(rs, 2);
      rs += __shfl_xor(rs, 4);
      rs += __shfl_xor(rs, 8);
      l_run[i] = l_run[i] * alpha + rs;
#pragma unroll
      for (int j = 0; j < 4; ++j) o_acc[i][j] *= alpha;
    }

    __syncthreads();  // everyone done reading Kt before P overwrites it
#pragma unroll
    for (int i = 0; i < 4; ++i)
#pragma unroll
      for (int j = 0; j < 4; ++j)
        KP[(tx * 4 + j) * 68 + (ty * 4 + i)] = s[i][j];  // Pt[c][r]
    __syncthreads();

    // ---- O += P @ V ----
#pragma unroll 8
    for (int j = 0; j < 64; ++j) {
      const float4 pv = *(const float4*)&KP[j * 68 + ty * 4];
      const float4 vv = *(const float4*)&Vs[j * 64 + tx * 4];
      const float pa[4] = {pv.x, pv.y, pv.z, pv.w};
      const float va[4] = {vv.x, vv.y, vv.z, vv.w};
#pragma unroll
      for (int i = 0; i < 4; ++i)
#pragma unroll
        for (int c = 0; c < 4; ++c) o_acc[i][c] += pa[i] * va[c];
    }
  }

  // epilogue: O[b, s, h*64+d], merged-head layout
  const int b = bh >> 4, h = bh & 15;
#pragma unroll
  for (int i = 0; i < 4; ++i) {
    const int gi = qt * 64 + ty * 4 + i;
    const float inv = 1.f / l_run[i];
    const float4 ov = make_float4(o_acc[i][0] * inv, o_acc[i][1] * inv,
                                  o_acc[i][2] * inv, o_acc[i][3] * inv);
    *(float4*)(O + ((size_t)(b * SEQ + gi) * EMB) + h * HD + tx * 4) = ov;
  }
}

// ---------------------------------------------------------------------------
extern "C" void kernel_launch(void* const* d_in, const int* in_sizes, int n_in,
                              void* d_out, int out_size, void* d_ws,
                              size_t ws_size, hipStream_t stream) {
  const float* q = (const float*)d_in[0];
  const float* k = (const float*)d_in[1];
  const float* v = (const float*)d_in[2];
  // d_in[3] = causal mask (tril by construction) -> predicate col>row instead
  const float* Wq = (const float*)d_in[4];
  const float* bq = (const float*)d_in[5];
  const float* Wk = (const float*)d_in[6];
  const float* bk = (const float*)d_in[7];
  const float* Wv = (const float*)d_in[8];
  const float* bv = (const float*)d_in[9];
  const float* Wo = (const float*)d_in[10];
  const float* bo = (const float*)d_in[11];
  float* out = (float*)d_out;
  float* ws = (float*)d_ws;

  const size_t bufElems = (size_t)BATCH * SEQ * EMB;  // 8388608
  float* Qb = ws;
  float* Kb = ws + bufElems;
  float* Vb = ws + 2 * bufElems;
  const bool big = ws_size >= 4 * bufElems * sizeof(float);
  float* AO = big ? ws + 3 * bufElems : out;  // attention output (merged heads)
  float* PO = big ? out : ws;                 // final projection destination

  const dim3 pgrid(EMB / 128, (BATCH * SEQ) / 128);  // (8, 64)
  const dim3 pblk(256);
  mha_proj_kernel<0><<<pgrid, pblk, 0, stream>>>(q, Wq, bq, Qb);
  mha_proj_kernel<0><<<pgrid, pblk, 0, stream>>>(k, Wk, bk, Kb);
  mha_proj_kernel<0><<<pgrid, pblk, 0, stream>>>(v, Wv, bv, Vb);

  mha_attn_kernel<<<dim3(SEQ / 64, BATCH * NH), 256, 0, stream>>>(Qb, Kb, Vb,
                                                                  AO);

  mha_proj_kernel<1><<<pgrid, pblk, 0, stream>>>(AO, Wo, bo, PO);
  if (!big)
    hipMemcpyAsync(out, PO, bufElems * sizeof(float), hipMemcpyDeviceToDevice,
                   stream);
}

// Round 2
// 820.156 us; speedup vs baseline: 2.1308x; 2.1308x over previous
//
#include <hip/hip_runtime.h>

#define SEQ   2048
#define EMB   1024
#define NH    16
#define HD    64
#define BATCH 4

typedef __attribute__((ext_vector_type(8))) short short8;   // 8 bf16 = 4 VGPR
typedef __attribute__((ext_vector_type(4))) float floatx4;  // MFMA acc

// bf16 round-to-nearest-even via integer trick (1 add, 1 shift-ish).
static __device__ __forceinline__ ushort f2bf_rne(float x) {
  unsigned u = __float_as_uint(x);
  unsigned r = u + 0x7FFFu + ((u >> 16) & 1u);
  return (ushort)(r >> 16);
}
static __device__ __forceinline__ float bf2f(ushort h) {
  return __uint_as_float(((unsigned)h) << 16);
}

// ---------------------------------------------------------------------------
// Split-bf16 projection GEMM: Y = X @ W^T + bias   (fp32 in, fp32 out)
// X: [M, EMB] row-major. W: [EMB, EMB] row-major (out_features, in_features).
// x = hi + lo (both bf16); X@W^T = XhiWhi + XhiWlo + XloWhi (lo*lo dropped).
// 128x128 tile, BK=32, 256 threads = 4 waves (2x2, 64x64 out each).
// MFMA 16x16x32_bf16; A-frag: lane reads row (l&15), k-chunk (l>>4)*8.
// LDS rows padded to 40 bf16 (80 B) for uniform bank spread on ds_read_b128.
// MODE 0: scatter Y into [b,h,s,d]. MODE 1: plain [m,n].
// ---------------------------------------------------------------------------
template <int MODE>
__global__ __launch_bounds__(256) void proj_mfma_kernel(
    const float* __restrict__ X, const float* __restrict__ W,
    const float* __restrict__ bias, float* __restrict__ Y) {
  __shared__ ushort Ahi[128 * 40], Alo[128 * 40];
  __shared__ ushort Bhi[128 * 40], Blo[128 * 40];

  const int t = threadIdx.x;
  const int lane = t & 63, wave = t >> 6;
  const int m0 = blockIdx.y * 128, n0 = blockIdx.x * 128;
  const int wm = (wave >> 1) * 64, wn = (wave & 1) * 64;  // wave's 64x64 quad
  const int fr = lane & 15, kg = lane >> 4;               // frag row/col, k-grp

  floatx4 acc[4][4];
#pragma unroll
  for (int i = 0; i < 4; ++i)
#pragma unroll
    for (int j = 0; j < 4; ++j)
#pragma unroll
      for (int r = 0; r < 4; ++r) acc[i][j][r] = 0.f;

#pragma unroll 1
  for (int k0 = 0; k0 < EMB; k0 += 32) {
    __syncthreads();  // prior iteration's frag reads complete
    // ---- stage A (X tile) and B (W tile): fp32 -> hi/lo bf16 in LDS ----
#pragma unroll
    for (int i = 0; i < 4; ++i) {
      const int f = t + 256 * i;  // 1024 float4 slots = 128 rows x 8
      const int row = f >> 3, kq = f & 7;
      {
        const float4 a =
            *(const float4*)(X + (size_t)(m0 + row) * EMB + k0 + kq * 4);
        const ushort h0 = f2bf_rne(a.x), h1 = f2bf_rne(a.y);
        const ushort h2 = f2bf_rne(a.z), h3 = f2bf_rne(a.w);
        const ushort l0 = f2bf_rne(a.x - bf2f(h0)), l1 = f2bf_rne(a.y - bf2f(h1));
        const ushort l2 = f2bf_rne(a.z - bf2f(h2)), l3 = f2bf_rne(a.w - bf2f(h3));
        uint2 hp, lp;
        hp.x = (uint)h0 | ((uint)h1 << 16);
        hp.y = (uint)h2 | ((uint)h3 << 16);
        lp.x = (uint)l0 | ((uint)l1 << 16);
        lp.y = (uint)l2 | ((uint)l3 << 16);
        *(uint2*)&Ahi[row * 40 + kq * 4] = hp;
        *(uint2*)&Alo[row * 40 + kq * 4] = lp;
      }
      {
        const float4 b =
            *(const float4*)(W + (size_t)(n0 + row) * EMB + k0 + kq * 4);
        const ushort h0 = f2bf_rne(b.x), h1 = f2bf_rne(b.y);
        const ushort h2 = f2bf_rne(b.z), h3 = f2bf_rne(b.w);
        const ushort l0 = f2bf_rne(b.x - bf2f(h0)), l1 = f2bf_rne(b.y - bf2f(h1));
        const ushort l2 = f2bf_rne(b.z - bf2f(h2)), l3 = f2bf_rne(b.w - bf2f(h3));
        uint2 hp, lp;
        hp.x = (uint)h0 | ((uint)h1 << 16);
        hp.y = (uint)h2 | ((uint)h3 << 16);
        lp.x = (uint)l0 | ((uint)l1 << 16);
        lp.y = (uint)l2 | ((uint)l3 << 16);
        *(uint2*)&Bhi[row * 40 + kq * 4] = hp;
        *(uint2*)&Blo[row * 40 + kq * 4] = lp;
      }
    }
    __syncthreads();

    // ---- fragments + MFMA ----
    short8 bhv[4], blv[4];
#pragma unroll
    for (int nf = 0; nf < 4; ++nf) {
      bhv[nf] = *(const short8*)&Bhi[(wn + nf * 16 + fr) * 40 + kg * 8];
      blv[nf] = *(const short8*)&Blo[(wn + nf * 16 + fr) * 40 + kg * 8];
    }
#pragma unroll
    for (int mf = 0; mf < 4; ++mf) {
      const short8 ah = *(const short8*)&Ahi[(wm + mf * 16 + fr) * 40 + kg * 8];
      const short8 al = *(const short8*)&Alo[(wm + mf * 16 + fr) * 40 + kg * 8];
#pragma unroll
      for (int nf = 0; nf < 4; ++nf) {
        acc[mf][nf] = __builtin_amdgcn_mfma_f32_16x16x32_bf16(ah, bhv[nf],
                                                              acc[mf][nf], 0, 0, 0);
        acc[mf][nf] = __builtin_amdgcn_mfma_f32_16x16x32_bf16(ah, blv[nf],
                                                              acc[mf][nf], 0, 0, 0);
        acc[mf][nf] = __builtin_amdgcn_mfma_f32_16x16x32_bf16(al, bhv[nf],
                                                              acc[mf][nf], 0, 0, 0);
      }
    }
  }

  // ---- epilogue: C/D layout col = lane&15, row = (lane>>4)*4 + reg ----
  const int rg = lane >> 4;
#pragma unroll
  for (int nf = 0; nf < 4; ++nf) {
    const int n = n0 + wn + nf * 16 + fr;
    const float bb = bias[n];
#pragma unroll
    for (int mf = 0; mf < 4; ++mf) {
#pragma unroll
      for (int r = 0; r < 4; ++r) {
        const int m = m0 + wm + mf * 16 + rg * 4 + r;
        const float val = acc[mf][nf][r] + bb;
        if (MODE == 0) {
          const int h = n >> 6, d = n & 63;
          const int b = m >> 11, s = m & (SEQ - 1);
          Y[(((size_t)(b * NH + h) * SEQ + s) * HD) + d] = val;
        } else {
          Y[(size_t)m * EMB + n] = val;
        }
      }
    }
  }
}

// ---------------------------------------------------------------------------
// Causal flash attention, fp32 (unchanged compute; heavy-first scheduling).
// grid = (B*NH, SEQ/64); qt iterated heavy-first so the 32-tile blocks launch
// first and equal-work blocks round-robin the 8 XCDs.
// ---------------------------------------------------------------------------
__global__ __launch_bounds__(256) void mha_attn_kernel(
    const float* __restrict__ Q, const float* __restrict__ K,
    const float* __restrict__ V, float* __restrict__ O) {
  __shared__ float Qt[64 * 64];  // Qt[d*64 + r]       = Q[r][d]
  __shared__ float KP[64 * 68];  // Kt[d*68 + j] = K[j][d]; later Pt[c*68 + r]
  __shared__ float Vs[64 * 64];  // Vs[j*64 + d]

  const int bh = blockIdx.x;
  const int qt = (gridDim.y - 1) - blockIdx.y;  // heavy tiles first
  const int t = threadIdx.x, tx = t & 15, ty = t >> 4;
  const size_t base = (size_t)bh * SEQ * HD;
  const float* Qb = Q + base + (size_t)qt * 64 * HD;
  const float* Kb = K + base;
  const float* Vb = V + base;

  {  // Q tile, transposed store
    const int j = t & 63, dg = t >> 6;
#pragma unroll
    for (int dd = 0; dd < 4; ++dd) {
      const int d4 = dg + dd * 4;
      const float4 v = *(const float4*)(Qb + (size_t)j * HD + d4 * 4);
      Qt[(d4 * 4 + 0) * 64 + j] = v.x;
      Qt[(d4 * 4 + 1) * 64 + j] = v.y;
      Qt[(d4 * 4 + 2) * 64 + j] = v.z;
      Qt[(d4 * 4 + 3) * 64 + j] = v.w;
    }
  }

  float m_run[4], l_run[4], o_acc[4][4];
#pragma unroll
  for (int i = 0; i < 4; ++i) {
    m_run[i] = -INFINITY;
    l_run[i] = 0.f;
#pragma unroll
    for (int j = 0; j < 4; ++j) o_acc[i][j] = 0.f;
  }

  for (int kt = 0; kt <= qt; ++kt) {
    __syncthreads();  // previous tile's P/V reads done before overwrite
    {                 // K transposed, V natural
      const int j = t & 63, dg = t >> 6;
      const float* srcK = Kb + (size_t)(kt * 64 + j) * HD;
#pragma unroll
      for (int dd = 0; dd < 4; ++dd) {
        const int d4 = dg + dd * 4;
        const float4 v = *(const float4*)(srcK + d4 * 4);
        KP[(d4 * 4 + 0) * 68 + j] = v.x;
        KP[(d4 * 4 + 1) * 68 + j] = v.y;
        KP[(d4 * 4 + 2) * 68 + j] = v.z;
        KP[(d4 * 4 + 3) * 68 + j] = v.w;
      }
      const int jv = t >> 4, d4 = t & 15;
#pragma unroll
      for (int it = 0; it < 4; ++it) {
        const int jr = jv + 16 * it;
        const float4 v =
            *(const float4*)(Vb + (size_t)(kt * 64 + jr) * HD + d4 * 4);
        *(float4*)&Vs[jr * 64 + d4 * 4] = v;
      }
    }
    __syncthreads();

    // ---- scores ----
    float s[4][4] = {{0.f, 0.f, 0.f, 0.f},
                     {0.f, 0.f, 0.f, 0.f},
                     {0.f, 0.f, 0.f, 0.f},
                     {0.f, 0.f, 0.f, 0.f}};
#pragma unroll 8
    for (int d = 0; d < 64; ++d) {
      const float4 qv = *(const float4*)&Qt[d * 64 + ty * 4];
      const float4 kv = *(const float4*)&KP[d * 68 + tx * 4];
      const float qa[4] = {qv.x, qv.y, qv.z, qv.w};
      const float ka[4] = {kv.x, kv.y, kv.z, kv.w};
#pragma unroll
      for (int i = 0; i < 4; ++i)
#pragma unroll
        for (int j = 0; j < 4; ++j) s[i][j] += qa[i] * ka[j];
    }

    const float scale = 0.125f;  // 1/sqrt(64)
#pragma unroll
    for (int i = 0; i < 4; ++i)
#pragma unroll
      for (int j = 0; j < 4; ++j) {
        float x = s[i][j] * scale;
        if (kt == qt && (tx * 4 + j) > (ty * 4 + i)) x = -1e9f;  // causal
        s[i][j] = x;
      }

    // ---- online softmax (row reduce over the 16 tx-lanes) ----
#pragma unroll
    for (int i = 0; i < 4; ++i) {
      float tm = fmaxf(fmaxf(s[i][0], s[i][1]), fmaxf(s[i][2], s[i][3]));
      tm = fmaxf(tm, __shfl_xor(tm, 1));
      tm = fmaxf(tm, __shfl_xor(tm, 2));
      tm = fmaxf(tm, __shfl_xor(tm, 4));
      tm = fmaxf(tm, __shfl_xor(tm, 8));
      const float mnew = fmaxf(m_run[i], tm);
      const float alpha = __expf(m_run[i] - mnew);
      m_run[i] = mnew;
      float rs = 0.f;
#pragma unroll
      for (int j = 0; j < 4; ++j) {
        s[i][j] = __expf(s[i][j] - mnew);
        rs += s[i][j];
      }
      rs += __shfl_xor(rs, 1);
      rs += __shfl_xor(rs, 2);
      rs += __shfl_xor(rs, 4);
      rs += __shfl_xor(rs, 8);
      l_run[i] = l_run[i] * alpha + rs;
#pragma unroll
      for (int j = 0; j < 4; ++j) o_acc[i][j] *= alpha;
    }

    __syncthreads();  // K reads done before P overwrites
#pragma unroll
    for (int i = 0; i < 4; ++i)
#pragma unroll
      for (int j = 0; j < 4; ++j)
        KP[(tx * 4 + j) * 68 + (ty * 4 + i)] = s[i][j];  // Pt[c][r]
    __syncthreads();

    // ---- O += P @ V ----
#pragma unroll 8
    for (int j = 0; j < 64; ++j) {
      const float4 pv = *(const float4*)&KP[j * 68 + ty * 4];
      const float4 vv = *(const float4*)&Vs[j * 64 + tx * 4];
      const float pa[4] = {pv.x, pv.y, pv.z, pv.w};
      const float va[4] = {vv.x, vv.y, vv.z, vv.w};
#pragma unroll
      for (int i = 0; i < 4; ++i)
#pragma unroll
        for (int c = 0; c < 4; ++c) o_acc[i][c] += pa[i] * va[c];
    }
  }

  // epilogue: O[b, s, h*64+d], merged-head layout
  const int b = bh >> 4, h = bh & 15;
#pragma unroll
  for (int i = 0; i < 4; ++i) {
    const int gi = qt * 64 + ty * 4 + i;
    const float inv = 1.f / l_run[i];
    const float4 ov = make_float4(o_acc[i][0] * inv, o_acc[i][1] * inv,
                                  o_acc[i][2] * inv, o_acc[i][3] * inv);
    *(float4*)(O + ((size_t)(b * SEQ + gi) * EMB) + h * HD + tx * 4) = ov;
  }
}

// ---------------------------------------------------------------------------
extern "C" void kernel_launch(void* const* d_in, const int* in_sizes, int n_in,
                              void* d_out, int out_size, void* d_ws,
                              size_t ws_size, hipStream_t stream) {
  const float* q = (const float*)d_in[0];
  const float* k = (const float*)d_in[1];
  const float* v = (const float*)d_in[2];
  // d_in[3] = causal mask (tril by construction) -> predicate col>row instead
  const float* Wq = (const float*)d_in[4];
  const float* bq = (const float*)d_in[5];
  const float* Wk = (const float*)d_in[6];
  const float* bk = (const float*)d_in[7];
  const float* Wv = (const float*)d_in[8];
  const float* bv = (const float*)d_in[9];
  const float* Wo = (const float*)d_in[10];
  const float* bo = (const float*)d_in[11];
  float* out = (float*)d_out;
  float* ws = (float*)d_ws;

  const size_t bufElems = (size_t)BATCH * SEQ * EMB;  // 8388608
  float* Qb = ws;
  float* Kb = ws + bufElems;
  float* Vb = ws + 2 * bufElems;
  const bool big = ws_size >= 4 * bufElems * sizeof(float);
  float* AO = big ? ws + 3 * bufElems : out;  // attention output (merged heads)
  float* PO = big ? out : ws;                 // final projection destination

  const dim3 pgrid(EMB / 128, (BATCH * SEQ) / 128);  // (8, 64)
  const dim3 pblk(256);
  proj_mfma_kernel<0><<<pgrid, pblk, 0, stream>>>(q, Wq, bq, Qb);
  proj_mfma_kernel<0><<<pgrid, pblk, 0, stream>>>(k, Wk, bk, Kb);
  proj_mfma_kernel<0><<<pgrid, pblk, 0, stream>>>(v, Wv, bv, Vb);

  mha_attn_kernel<<<dim3(BATCH * NH, SEQ / 64), 256, 0, stream>>>(Qb, Kb, Vb,
                                                                  AO);

  proj_mfma_kernel<1><<<pgrid, pblk, 0, stream>>>(AO, Wo, bo, PO);
  if (!big)
    hipMemcpyAsync(out, PO, bufElems * sizeof(float), hipMemcpyDeviceToDevice,
                   stream);
}

// Round 3
// 507.461 us; speedup vs baseline: 3.4438x; 1.6162x over previous
//
#include <hip/hip_runtime.h>

#define SEQ   2048
#define EMB   1024
#define NH    16
#define HD    64
#define BATCH 4

typedef __attribute__((ext_vector_type(8))) short short8;   // 8 bf16 = 4 VGPR
typedef __attribute__((ext_vector_type(4))) float floatx4;  // MFMA acc

// bf16 round-to-nearest-even.
static __device__ __forceinline__ ushort f2bf_rne(float x) {
  unsigned u = __float_as_uint(x);
  unsigned r = u + 0x7FFFu + ((u >> 16) & 1u);
  return (ushort)(r >> 16);
}
static __device__ __forceinline__ float bf2f(ushort h) {
  return __uint_as_float(((unsigned)h) << 16);
}

// ---------------------------------------------------------------------------
// Split-bf16 projection GEMM: Y = X @ W^T + bias (unchanged from round 2).
// ---------------------------------------------------------------------------
template <int MODE>
__global__ __launch_bounds__(256) void proj_mfma_kernel(
    const float* __restrict__ X, const float* __restrict__ W,
    const float* __restrict__ bias, float* __restrict__ Y) {
  __shared__ ushort Ahi[128 * 40], Alo[128 * 40];
  __shared__ ushort Bhi[128 * 40], Blo[128 * 40];

  const int t = threadIdx.x;
  const int lane = t & 63, wave = t >> 6;
  const int m0 = blockIdx.y * 128, n0 = blockIdx.x * 128;
  const int wm = (wave >> 1) * 64, wn = (wave & 1) * 64;
  const int fr = lane & 15, kg = lane >> 4;

  floatx4 acc[4][4];
#pragma unroll
  for (int i = 0; i < 4; ++i)
#pragma unroll
    for (int j = 0; j < 4; ++j)
#pragma unroll
      for (int r = 0; r < 4; ++r) acc[i][j][r] = 0.f;

#pragma unroll 1
  for (int k0 = 0; k0 < EMB; k0 += 32) {
    __syncthreads();
#pragma unroll
    for (int i = 0; i < 4; ++i) {
      const int f = t + 256 * i;
      const int row = f >> 3, kq = f & 7;
      {
        const float4 a =
            *(const float4*)(X + (size_t)(m0 + row) * EMB + k0 + kq * 4);
        const ushort h0 = f2bf_rne(a.x), h1 = f2bf_rne(a.y);
        const ushort h2 = f2bf_rne(a.z), h3 = f2bf_rne(a.w);
        const ushort l0 = f2bf_rne(a.x - bf2f(h0)), l1 = f2bf_rne(a.y - bf2f(h1));
        const ushort l2 = f2bf_rne(a.z - bf2f(h2)), l3 = f2bf_rne(a.w - bf2f(h3));
        uint2 hp, lp;
        hp.x = (uint)h0 | ((uint)h1 << 16);
        hp.y = (uint)h2 | ((uint)h3 << 16);
        lp.x = (uint)l0 | ((uint)l1 << 16);
        lp.y = (uint)l2 | ((uint)l3 << 16);
        *(uint2*)&Ahi[row * 40 + kq * 4] = hp;
        *(uint2*)&Alo[row * 40 + kq * 4] = lp;
      }
      {
        const float4 b =
            *(const float4*)(W + (size_t)(n0 + row) * EMB + k0 + kq * 4);
        const ushort h0 = f2bf_rne(b.x), h1 = f2bf_rne(b.y);
        const ushort h2 = f2bf_rne(b.z), h3 = f2bf_rne(b.w);
        const ushort l0 = f2bf_rne(b.x - bf2f(h0)), l1 = f2bf_rne(b.y - bf2f(h1));
        const ushort l2 = f2bf_rne(b.z - bf2f(h2)), l3 = f2bf_rne(b.w - bf2f(h3));
        uint2 hp, lp;
        hp.x = (uint)h0 | ((uint)h1 << 16);
        hp.y = (uint)h2 | ((uint)h3 << 16);
        lp.x = (uint)l0 | ((uint)l1 << 16);
        lp.y = (uint)l2 | ((uint)l3 << 16);
        *(uint2*)&Bhi[row * 40 + kq * 4] = hp;
        *(uint2*)&Blo[row * 40 + kq * 4] = lp;
      }
    }
    __syncthreads();

    short8 bhv[4], blv[4];
#pragma unroll
    for (int nf = 0; nf < 4; ++nf) {
      bhv[nf] = *(const short8*)&Bhi[(wn + nf * 16 + fr) * 40 + kg * 8];
      blv[nf] = *(const short8*)&Blo[(wn + nf * 16 + fr) * 40 + kg * 8];
    }
#pragma unroll
    for (int mf = 0; mf < 4; ++mf) {
      const short8 ah = *(const short8*)&Ahi[(wm + mf * 16 + fr) * 40 + kg * 8];
      const short8 al = *(const short8*)&Alo[(wm + mf * 16 + fr) * 40 + kg * 8];
#pragma unroll
      for (int nf = 0; nf < 4; ++nf) {
        acc[mf][nf] = __builtin_amdgcn_mfma_f32_16x16x32_bf16(ah, bhv[nf],
                                                              acc[mf][nf], 0, 0, 0);
        acc[mf][nf] = __builtin_amdgcn_mfma_f32_16x16x32_bf16(ah, blv[nf],
                                                              acc[mf][nf], 0, 0, 0);
        acc[mf][nf] = __builtin_amdgcn_mfma_f32_16x16x32_bf16(al, bhv[nf],
                                                              acc[mf][nf], 0, 0, 0);
      }
    }
  }

  const int rg = lane >> 4;
#pragma unroll
  for (int nf = 0; nf < 4; ++nf) {
    const int n = n0 + wn + nf * 16 + fr;
    const float bb = bias[n];
#pragma unroll
    for (int mf = 0; mf < 4; ++mf) {
#pragma unroll
      for (int r = 0; r < 4; ++r) {
        const int m = m0 + wm + mf * 16 + rg * 4 + r;
        const float val = acc[mf][nf][r] + bb;
        if (MODE == 0) {
          const int h = n >> 6, d = n & 63;
          const int b = m >> 11, s = m & (SEQ - 1);
          Y[(((size_t)(b * NH + h) * SEQ + s) * HD) + d] = val;
        } else {
          Y[(size_t)m * EMB + n] = val;
        }
      }
    }
  }
}

// ---------------------------------------------------------------------------
// Split-bf16 MFMA causal flash attention.
// Block = (bh, 128-row q-tile), 4 waves x 32 q-rows. K-tile = 64 cols.
// Q (pre-scaled 1/8) in registers hi/lo. K natural [kv][d] in LDS hi/lo.
// V transposed [d][kv] in LDS hi/lo with chunk swizzle (c + 2d)&7.
// P round-trips via LDS [q][kv] hi/lo (per-wave private rows).
// Online softmax over 16-lane row groups. Output merged [b, s, h*64+d].
// ---------------------------------------------------------------------------
__global__ __launch_bounds__(256, 2) void attn_mfma_kernel(
    const float* __restrict__ Q, const float* __restrict__ K,
    const float* __restrict__ V, float* __restrict__ O) {
  __shared__ __align__(16) ushort Khi[64 * 72], Klo[64 * 72];
  __shared__ __align__(16) ushort Vthi[64 * 72], Vtlo[64 * 72];
  __shared__ __align__(16) ushort Phi[128 * 72], Plo[128 * 72];

  const int bh = blockIdx.x;
  const int qt = (gridDim.y - 1) - blockIdx.y;  // heavy q-tiles first
  const int t = threadIdx.x;
  const int lane = t & 63, wave = t >> 6;
  const int fr = lane & 15, kg = lane >> 4;
  const size_t base = (size_t)bh * SEQ * HD;
  const int q0 = qt * 128 + wave * 32;  // wave's first global q row

  // ---- Q fragments, pre-scaled by 1/sqrt(64)=0.125 (exact), hi/lo ----
  short8 qh[2][2], ql[2][2];
#pragma unroll
  for (int mf = 0; mf < 2; ++mf)
#pragma unroll
    for (int ks = 0; ks < 2; ++ks) {
      const float* src =
          Q + base + (size_t)(q0 + mf * 16 + fr) * HD + ks * 32 + kg * 8;
      const float4 a = *(const float4*)src;
      const float4 b = *(const float4*)(src + 4);
      const float xv[8] = {a.x * 0.125f, a.y * 0.125f, a.z * 0.125f,
                           a.w * 0.125f, b.x * 0.125f, b.y * 0.125f,
                           b.z * 0.125f, b.w * 0.125f};
      short8 h, l;
#pragma unroll
      for (int j = 0; j < 8; ++j) {
        const ushort hh = f2bf_rne(xv[j]);
        h[j] = (short)hh;
        l[j] = (short)f2bf_rne(xv[j] - bf2f(hh));
      }
      qh[mf][ks] = h;
      ql[mf][ks] = l;
    }

  floatx4 oacc[2][4];  // [mf][nf=d-frag]
  float m_run[2][4], l_run[2][4];
#pragma unroll
  for (int mf = 0; mf < 2; ++mf) {
#pragma unroll
    for (int nf = 0; nf < 4; ++nf)
#pragma unroll
      for (int r = 0; r < 4; ++r) oacc[mf][nf][r] = 0.f;
#pragma unroll
    for (int r = 0; r < 4; ++r) {
      m_run[mf][r] = -INFINITY;
      l_run[mf][r] = 0.f;
    }
  }

  const int nkt = 2 * qt + 2;
  const float* Kb = K + base;
  const float* Vb = V + base;

#pragma unroll 1
  for (int kt = 0; kt < nkt; ++kt) {
    __syncthreads();  // prior tile's K/Vt reads complete
    // ---- stage K natural [kv][d], hi/lo, uint2 writes ----
    const float* Ksrc = Kb + (size_t)kt * 64 * HD;
#pragma unroll
    for (int i = 0; i < 4; ++i) {
      const int f = t + 256 * i;  // 1024 float4 chunks: 64 rows x 16
      const int row = f >> 4, ch = f & 15;
      const float4 x = *(const float4*)(Ksrc + (size_t)row * HD + ch * 4);
      const ushort h0 = f2bf_rne(x.x), h1 = f2bf_rne(x.y);
      const ushort h2 = f2bf_rne(x.z), h3 = f2bf_rne(x.w);
      const ushort l0 = f2bf_rne(x.x - bf2f(h0)), l1 = f2bf_rne(x.y - bf2f(h1));
      const ushort l2 = f2bf_rne(x.z - bf2f(h2)), l3 = f2bf_rne(x.w - bf2f(h3));
      uint2 hp, lp;
      hp.x = (uint)h0 | ((uint)h1 << 16);
      hp.y = (uint)h2 | ((uint)h3 << 16);
      lp.x = (uint)l0 | ((uint)l1 << 16);
      lp.y = (uint)l2 | ((uint)l3 << 16);
      *(uint2*)&Khi[row * 72 + ch * 4] = hp;
      *(uint2*)&Klo[row * 72 + ch * 4] = lp;
    }
    // ---- stage V transposed [d][kv], swizzled chunks; kv = lane ----
    const float* Vsrc = Vb + (size_t)kt * 64 * HD;
    {
      const int cbase = lane >> 3, k7 = lane & 7;
#pragma unroll
      for (int i = 0; i < 4; ++i) {
        const int dchunk = wave + 4 * i;  // 0..15
        const float4 x = *(const float4*)(Vsrc + (size_t)lane * HD + dchunk * 4);
        const float xv[4] = {x.x, x.y, x.z, x.w};
#pragma unroll
        for (int dd = 0; dd < 4; ++dd) {
          const int d = dchunk * 4 + dd;
          const int idx = d * 72 + (((cbase + 2 * d) & 7) << 3) + k7;
          const ushort h = f2bf_rne(xv[dd]);
          Vthi[idx] = h;
          Vtlo[idx] = f2bf_rne(xv[dd] - bf2f(h));
        }
      }
    }
    __syncthreads();

    const int c0 = kt * 64;       // first k-column of tile
    if (c0 > q0 + 31) continue;   // fully masked for this wave (barriers done)

    // ---- S = Q K^T (split-bf16, 3 MFMA) ----
    floatx4 s[2][4];
#pragma unroll
    for (int mf = 0; mf < 2; ++mf)
#pragma unroll
      for (int nf = 0; nf < 4; ++nf)
#pragma unroll
        for (int r = 0; r < 4; ++r) s[mf][nf][r] = 0.f;

#pragma unroll
    for (int ks = 0; ks < 2; ++ks) {
      short8 kh[4], kl[4];
#pragma unroll
      for (int nf = 0; nf < 4; ++nf) {
        kh[nf] = *(const short8*)&Khi[(nf * 16 + fr) * 72 + ks * 32 + kg * 8];
        kl[nf] = *(const short8*)&Klo[(nf * 16 + fr) * 72 + ks * 32 + kg * 8];
      }
#pragma unroll
      for (int mf = 0; mf < 2; ++mf)
#pragma unroll
        for (int nf = 0; nf < 4; ++nf) {
          s[mf][nf] = __builtin_amdgcn_mfma_f32_16x16x32_bf16(
              qh[mf][ks], kh[nf], s[mf][nf], 0, 0, 0);
          s[mf][nf] = __builtin_amdgcn_mfma_f32_16x16x32_bf16(
              qh[mf][ks], kl[nf], s[mf][nf], 0, 0, 0);
          s[mf][nf] = __builtin_amdgcn_mfma_f32_16x16x32_bf16(
              ql[mf][ks], kh[nf], s[mf][nf], 0, 0, 0);
        }
    }

    // ---- causal mask (edge tiles only) ----
    if (c0 + 63 > q0) {
#pragma unroll
      for (int mf = 0; mf < 2; ++mf)
#pragma unroll
        for (int nf = 0; nf < 4; ++nf)
#pragma unroll
          for (int r = 0; r < 4; ++r) {
            const int row = q0 + mf * 16 + kg * 4 + r;
            const int col = c0 + nf * 16 + fr;
            if (col > row) s[mf][nf][r] = -1e9f;
          }
    }

    // ---- online softmax + P pack to LDS ----
#pragma unroll
    for (int mf = 0; mf < 2; ++mf)
#pragma unroll
      for (int r = 0; r < 4; ++r) {
        float v0 = s[mf][0][r], v1 = s[mf][1][r];
        float v2 = s[mf][2][r], v3 = s[mf][3][r];
        float tm = fmaxf(fmaxf(v0, v1), fmaxf(v2, v3));
        tm = fmaxf(tm, __shfl_xor(tm, 1));
        tm = fmaxf(tm, __shfl_xor(tm, 2));
        tm = fmaxf(tm, __shfl_xor(tm, 4));
        tm = fmaxf(tm, __shfl_xor(tm, 8));
        const float mnew = fmaxf(m_run[mf][r], tm);
        const float alpha = __expf(m_run[mf][r] - mnew);
        m_run[mf][r] = mnew;
        const float p0 = __expf(v0 - mnew), p1 = __expf(v1 - mnew);
        const float p2 = __expf(v2 - mnew), p3 = __expf(v3 - mnew);
        float rs = p0 + p1 + p2 + p3;
        rs += __shfl_xor(rs, 1);
        rs += __shfl_xor(rs, 2);
        rs += __shfl_xor(rs, 4);
        rs += __shfl_xor(rs, 8);
        l_run[mf][r] = l_run[mf][r] * alpha + rs;
        const int qrow = wave * 32 + mf * 16 + kg * 4 + r;
        const float pv[4] = {p0, p1, p2, p3};
#pragma unroll
        for (int nf = 0; nf < 4; ++nf) {
          const ushort h = f2bf_rne(pv[nf]);
          Phi[qrow * 72 + nf * 16 + fr] = h;
          Plo[qrow * 72 + nf * 16 + fr] = f2bf_rne(pv[nf] - bf2f(h));
        }
#pragma unroll
        for (int nf = 0; nf < 4; ++nf) oacc[mf][nf][r] *= alpha;
      }

    // ---- O += P V (split-bf16) ----
#pragma unroll
    for (int ks = 0; ks < 2; ++ks) {
      short8 ph[2], pl[2];
#pragma unroll
      for (int mf = 0; mf < 2; ++mf) {
        const int qrow = wave * 32 + mf * 16 + fr;
        ph[mf] = *(const short8*)&Phi[qrow * 72 + ks * 32 + kg * 8];
        pl[mf] = *(const short8*)&Plo[qrow * 72 + ks * 32 + kg * 8];
      }
#pragma unroll
      for (int nf = 0; nf < 4; ++nf) {
        const int d = nf * 16 + fr;
        const int cc = ks * 4 + kg;
        const int idx = d * 72 + (((cc + 2 * d) & 7) << 3);
        const short8 vh = *(const short8*)&Vthi[idx];
        const short8 vl = *(const short8*)&Vtlo[idx];
#pragma unroll
        for (int mf = 0; mf < 2; ++mf) {
          oacc[mf][nf] = __builtin_amdgcn_mfma_f32_16x16x32_bf16(
              ph[mf], vh, oacc[mf][nf], 0, 0, 0);
          oacc[mf][nf] = __builtin_amdgcn_mfma_f32_16x16x32_bf16(
              ph[mf], vl, oacc[mf][nf], 0, 0, 0);
          oacc[mf][nf] = __builtin_amdgcn_mfma_f32_16x16x32_bf16(
              pl[mf], vh, oacc[mf][nf], 0, 0, 0);
        }
      }
    }
  }

  // ---- epilogue: O[b, s, h*64 + d] merged layout ----
  const int b = bh >> 4, h = bh & 15;
#pragma unroll
  for (int mf = 0; mf < 2; ++mf)
#pragma unroll
    for (int r = 0; r < 4; ++r) {
      const int grow = q0 + mf * 16 + kg * 4 + r;
      const float inv = 1.f / l_run[mf][r];
      float* dst = O + (size_t)(b * SEQ + grow) * EMB + h * HD;
#pragma unroll
      for (int nf = 0; nf < 4; ++nf) dst[nf * 16 + fr] = oacc[mf][nf][r] * inv;
    }
}

// ---------------------------------------------------------------------------
extern "C" void kernel_launch(void* const* d_in, const int* in_sizes, int n_in,
                              void* d_out, int out_size, void* d_ws,
                              size_t ws_size, hipStream_t stream) {
  const float* q = (const float*)d_in[0];
  const float* k = (const float*)d_in[1];
  const float* v = (const float*)d_in[2];
  // d_in[3] = causal mask (tril by construction) -> predicate col>row instead
  const float* Wq = (const float*)d_in[4];
  const float* bq = (const float*)d_in[5];
  const float* Wk = (const float*)d_in[6];
  const float* bk = (const float*)d_in[7];
  const float* Wv = (const float*)d_in[8];
  const float* bv = (const float*)d_in[9];
  const float* Wo = (const float*)d_in[10];
  const float* bo = (const float*)d_in[11];
  float* out = (float*)d_out;
  float* ws = (float*)d_ws;

  const size_t bufElems = (size_t)BATCH * SEQ * EMB;  // 8388608
  float* Qb = ws;
  float* Kb = ws + bufElems;
  float* Vb = ws + 2 * bufElems;
  const bool big = ws_size >= 4 * bufElems * sizeof(float);
  float* AO = big ? ws + 3 * bufElems : out;
  float* PO = big ? out : ws;

  const dim3 pgrid(EMB / 128, (BATCH * SEQ) / 128);
  const dim3 pblk(256);
  proj_mfma_kernel<0><<<pgrid, pblk, 0, stream>>>(q, Wq, bq, Qb);
  proj_mfma_kernel<0><<<pgrid, pblk, 0, stream>>>(k, Wk, bk, Kb);
  proj_mfma_kernel<0><<<pgrid, pblk, 0, stream>>>(v, Wv, bv, Vb);

  attn_mfma_kernel<<<dim3(BATCH * NH, SEQ / 128), 256, 0, stream>>>(Qb, Kb, Vb,
                                                                    AO);

  proj_mfma_kernel<1><<<pgrid, pblk, 0, stream>>>(AO, Wo, bo, PO);
  if (!big)
    hipMemcpyAsync(out, PO, bufElems * sizeof(float), hipMemcpyDeviceToDevice,
                   stream);
}